// Round 1
// baseline (375.223 us; speedup 1.0000x reference)
//
#include <hip/hip_runtime.h>
#include <hip/hip_bf16.h>
#include <stdint.h>

typedef int v4i __attribute__((ext_vector_type(4)));

#define GPTR(p) ((const __attribute__((address_space(1))) void*)(p))
#define LPTR(p) ((__attribute__((address_space(3))) void*)(p))

__device__ __forceinline__ float wave_max(float m) {
#pragma unroll
  for (int off = 32; off > 0; off >>= 1)
    m = fmaxf(m, __shfl_xor(m, off, 64));
  return m;
}

__global__ void zero_scalars_kernel(unsigned* p) {
  if (threadIdx.x < 8) p[threadIdx.x] = 0u;
}

// absmax of src[i] * (*smul) (smul==nullptr -> 1.0), result as float bits via atomicMax
__global__ void absmax_kernel(const float* __restrict__ src, int n4,
                              const float* __restrict__ smul,
                              unsigned* __restrict__ dst) {
  const float4* s4 = (const float4*)src;
  const float s = smul ? smul[0] : 1.0f;
  float m = 0.0f;
  const int stride = gridDim.x * blockDim.x;
  for (int i = blockIdx.x * blockDim.x + threadIdx.x; i < n4; i += stride) {
    float4 v = s4[i];
    m = fmaxf(m, fabsf(v.x * s));
    m = fmaxf(m, fabsf(v.y * s));
    m = fmaxf(m, fabsf(v.z * s));
    m = fmaxf(m, fabsf(v.w * s));
  }
  m = wave_max(m);
  if ((threadIdx.x & 63) == 0) atomicMax(dst, __float_as_uint(m));
}

// q = rint(clip((v*smul)/scale, -128, 127)), scale = maxbits/127
__global__ void quantize_kernel(const float* __restrict__ src, int n4,
                                const float* __restrict__ smul,
                                const unsigned* __restrict__ maxbits,
                                int8_t* __restrict__ dst) {
  const float4* s4 = (const float4*)src;
  char4* d4 = (char4*)dst;
  const float s = smul ? smul[0] : 1.0f;
  const float scale = __uint_as_float(maxbits[0]) / 127.0f;
  const int stride = gridDim.x * blockDim.x;
  for (int i = blockIdx.x * blockDim.x + threadIdx.x; i < n4; i += stride) {
    float4 v = s4[i];
    char4 q;
    q.x = (signed char)(int)rintf(fminf(fmaxf((v.x * s) / scale, -128.0f), 127.0f));
    q.y = (signed char)(int)rintf(fminf(fmaxf((v.y * s) / scale, -128.0f), 127.0f));
    q.z = (signed char)(int)rintf(fminf(fmaxf((v.z * s) / scale, -128.0f), 127.0f));
    q.w = (signed char)(int)rintf(fminf(fmaxf((v.w * s) / scale, -128.0f), 127.0f));
    d4[i] = q;
  }
}

// C = A[M,K] @ B[N,K]^T, int8 inputs, int32 accumulate via MFMA.
// EPI 0: h=(acc+b1)*s1, g=gelu(h), block absmax(g) -> hmax (no store)
// EPI 1: same g, store qh = rint(clip(g/s_h)) int8
// EPI 2: store out = (acc+b2)*(sw2*sx2) f32
template <int EPI>
__global__ __launch_bounds__(256, 2)
void gemm_i8_kernel(const int8_t* __restrict__ A, const int8_t* __restrict__ B,
                    const float* __restrict__ bias,
                    const unsigned* __restrict__ scal,
                    unsigned* __restrict__ hmax,
                    int8_t* __restrict__ out_i8,
                    float* __restrict__ out_f32,
                    int N, int K) {
  __shared__ __align__(16) int8_t lA[2][128 * 128];
  __shared__ __align__(16) int8_t lB[2][128 * 128];

  const int t = threadIdx.x;
  const int lane = t & 63;
  const int wave = t >> 6;
  const int wr = wave >> 1;   // 2x2 wave grid, each wave 64x64
  const int wc = wave & 1;
  const size_t m0 = (size_t)blockIdx.x * 128;
  const int n0 = blockIdx.y * 128;

  const int8_t* Ab = A + m0 * (size_t)K;
  const int8_t* Bb = B + (size_t)n0 * (size_t)K;

  v4i acc[4][4] = {};

  const int KT = K >> 7;  // BK = 128

  // Stage one 128x128 i8 tile of A and B into LDS buf.
  // LDS layout: [row][slot] with slot = k/16, stored XOR-swizzled: data for
  // k-slot ss lives at lds slot ss^(row&7). global_load_lds writes linearly
  // (wave base + lane*16), so we pre-permute the SOURCE address (rule #21).
  auto stage = [&](int buf, int kt) {
    const int8_t* ga = Ab + kt * 128;
    const int8_t* gb = Bb + kt * 128;
#pragma unroll
    for (int p = 0; p < 4; ++p) {
      const int o = p * 4096 + t * 16;            // linear LDS byte this lane fills
      const int row = o >> 7;                     // tile row (128B rows)
      const int ss = ((o >> 4) & 7) ^ (row & 7);  // which k-slot belongs here
      const int ub = p * 4096 + (t & 192) * 16;   // wave-uniform LDS base
      __builtin_amdgcn_global_load_lds(GPTR(ga + (size_t)row * K + ss * 16),
                                       LPTR(&lA[buf][ub]), 16, 0, 0);
      __builtin_amdgcn_global_load_lds(GPTR(gb + (size_t)row * K + ss * 16),
                                       LPTR(&lB[buf][ub]), 16, 0, 0);
    }
  };

  auto compute = [&](int buf) {
    const int r15 = lane & 15;
    const int q4 = lane >> 4;
    v4i af[4][2], bf[4][2];
#pragma unroll
    for (int fr = 0; fr < 4; ++fr) {
      const int row = wr * 64 + fr * 16 + r15;
#pragma unroll
      for (int kk = 0; kk < 2; ++kk) {
        const int slot = kk * 4 + q4;
        af[fr][kk] = *(const v4i*)(&lA[buf][row * 128 + ((slot ^ (row & 7)) * 16)]);
      }
    }
#pragma unroll
    for (int fc = 0; fc < 4; ++fc) {
      const int row = wc * 64 + fc * 16 + r15;
#pragma unroll
      for (int kk = 0; kk < 2; ++kk) {
        const int slot = kk * 4 + q4;
        bf[fc][kk] = *(const v4i*)(&lB[buf][row * 128 + ((slot ^ (row & 7)) * 16)]);
      }
    }
#pragma unroll
    for (int fr = 0; fr < 4; ++fr)
#pragma unroll
      for (int fc = 0; fc < 4; ++fc) {
        acc[fr][fc] = __builtin_amdgcn_mfma_i32_16x16x64_i8(af[fr][0], bf[fc][0], acc[fr][fc], 0, 0, 0);
        acc[fr][fc] = __builtin_amdgcn_mfma_i32_16x16x64_i8(af[fr][1], bf[fc][1], acc[fr][fc], 0, 0, 0);
      }
  };

  stage(0, 0);
  asm volatile("s_waitcnt vmcnt(0)" ::: "memory");
  __syncthreads();
  int cur = 0;
  for (int kt = 0; kt + 1 < KT; ++kt) {
    stage(cur ^ 1, kt + 1);
    compute(cur);
    __syncthreads();  // drains vmcnt+lgkmcnt before barrier
    cur ^= 1;
  }
  compute(cur);

  // Epilogue. C/D mapping: col = lane&15, row = (lane>>4)*4 + reg.
  const int r15 = lane & 15;
  const int rb = (lane >> 4) * 4;

  if constexpr (EPI == 0 || EPI == 1) {
    const float sx = __uint_as_float(scal[0]) / 127.0f;  // max|x*s_x|/127
    const float sw = __uint_as_float(scal[1]) / 127.0f;  // max|w1|/127
    const float s1 = sw * sx;
    float sh = 1.0f;
    if constexpr (EPI == 1) sh = __uint_as_float(scal[3]) / 127.0f;
    float lm = 0.0f;
#pragma unroll
    for (int fc = 0; fc < 4; ++fc) {
      const int col = n0 + wc * 64 + fc * 16 + r15;
      const float bv = bias[col];
#pragma unroll
      for (int fr = 0; fr < 4; ++fr) {
#pragma unroll
        for (int r = 0; r < 4; ++r) {
          const size_t row = m0 + (size_t)(wr * 64 + fr * 16 + rb + r);
          const float f = ((float)acc[fr][fc][r] + bv) * s1;
          const float e = erff(f / 1.4142135381698608f);  // f32(sqrt(2))
          const float g = (f * (e + 1.0f)) * 0.5f;        // exact GELU, as jax.nn.gelu
          if constexpr (EPI == 0) {
            lm = fmaxf(lm, fabsf(g));
          } else {
            const float qv = rintf(fminf(fmaxf(g / sh, -128.0f), 127.0f));
            out_i8[row * (size_t)N + col] = (int8_t)(int)qv;
          }
        }
      }
    }
    if constexpr (EPI == 0) {
      lm = wave_max(lm);
      if (lane == 0) atomicMax(hmax, __float_as_uint(lm));
    }
  } else {
    const float sw2 = __uint_as_float(scal[2]) / 127.0f;  // max|w2|/127
    const float sh = __uint_as_float(scal[3]) / 127.0f;   // s_h
    const float x2max = 127.0f * sh;                      // max|qh*s_h|
    const float sx2 = x2max / 127.0f;                     // fc2-internal act scale
    const float s2 = sw2 * sx2;
#pragma unroll
    for (int fc = 0; fc < 4; ++fc) {
      const int col = n0 + wc * 64 + fc * 16 + r15;
      const float bv = bias[col];
#pragma unroll
      for (int fr = 0; fr < 4; ++fr) {
#pragma unroll
        for (int r = 0; r < 4; ++r) {
          const size_t row = m0 + (size_t)(wr * 64 + fr * 16 + rb + r);
          out_f32[row * (size_t)N + col] = ((float)acc[fr][fc][r] + bv) * s2;
        }
      }
    }
  }
}

extern "C" void kernel_launch(void* const* d_in, const int* in_sizes, int n_in,
                              void* d_out, int out_size, void* d_ws, size_t ws_size,
                              hipStream_t stream) {
  const float* x   = (const float*)d_in[0];
  const float* sxp = (const float*)d_in[1];  // act_scaling_factor (1 elem)
  const float* w1  = (const float*)d_in[2];
  const float* b1  = (const float*)d_in[3];
  const float* w2  = (const float*)d_in[4];
  const float* b2  = (const float*)d_in[5];

  const int H = in_sizes[3];      // 1536
  const int D = in_sizes[5];      // 384
  const int M = in_sizes[0] / D;  // 25216 = 197*128

  uint8_t* ws = (uint8_t*)d_ws;
  unsigned* scal = (unsigned*)ws;  // [0]=max|x2| [1]=max|w1| [2]=max|w2| [3]=max|gelu(h)|
  size_t off = 256;
  int8_t* qx  = (int8_t*)(ws + off); off += (size_t)M * D;
  int8_t* qw1 = (int8_t*)(ws + off); off += (size_t)H * D;
  int8_t* qw2 = (int8_t*)(ws + off); off += (size_t)D * H;
  int8_t* qh  = (int8_t*)(ws + off); off += (size_t)M * H;
  (void)ws_size; (void)n_in; (void)out_size;

  zero_scalars_kernel<<<1, 64, 0, stream>>>(scal);

  absmax_kernel<<<dim3(1024), dim3(256), 0, stream>>>(x, M * D / 4, sxp, scal + 0);
  absmax_kernel<<<dim3(256), dim3(256), 0, stream>>>(w1, H * D / 4, nullptr, scal + 1);
  absmax_kernel<<<dim3(256), dim3(256), 0, stream>>>(w2, D * H / 4, nullptr, scal + 2);

  quantize_kernel<<<dim3(2048), dim3(256), 0, stream>>>(x, M * D / 4, sxp, scal + 0, qx);
  quantize_kernel<<<dim3(256), dim3(256), 0, stream>>>(w1, H * D / 4, nullptr, scal + 1, qw1);
  quantize_kernel<<<dim3(256), dim3(256), 0, stream>>>(w2, D * H / 4, nullptr, scal + 2, qw2);

  dim3 blk(256);
  dim3 g1(M / 128, H / 128);  // 197 x 12
  // pass A: absmax of gelu(fc1) only
  gemm_i8_kernel<0><<<g1, blk, 0, stream>>>(qx, qw1, b1, scal, scal + 3, nullptr, nullptr, H, D);
  // pass B: recompute fc1, quantize to qh
  gemm_i8_kernel<1><<<g1, blk, 0, stream>>>(qx, qw1, b1, scal, nullptr, qh, nullptr, H, D);

  dim3 g2(M / 128, D / 128);  // 197 x 3
  gemm_i8_kernel<2><<<g2, blk, 0, stream>>>(qh, qw2, b2, scal, nullptr, nullptr, (float*)d_out, D, H);
}

// Round 2
// 166.136 us; speedup vs baseline: 2.2585x; 2.2585x over previous
//
#include <hip/hip_runtime.h>
#include <hip/hip_bf16.h>
#include <stdint.h>

typedef int v4i __attribute__((ext_vector_type(4)));

#define GPTR(p) ((const __attribute__((address_space(1))) void*)(p))
#define LPTR(p) ((__attribute__((address_space(3))) void*)(p))

__device__ __forceinline__ float wave_max(float m) {
#pragma unroll
  for (int off = 32; off > 0; off >>= 1)
    m = fmaxf(m, __shfl_xor(m, off, 64));
  return m;
}

// branch-free erf (Abramowitz-Stegun 7.1.26), |err| <= 1.5e-7 absolute
__device__ __forceinline__ float fast_erf(float x) {
  const float ax = fabsf(x);
  const float t = __builtin_amdgcn_rcpf(fmaf(0.3275911f, ax, 1.0f));
  float p = fmaf(1.061405429f, t, -1.453152027f);
  p = fmaf(p, t, 1.421413741f);
  p = fmaf(p, t, -0.284496736f);
  p = fmaf(p, t, 0.254829592f);
  const float e = __expf(-ax * ax);
  const float r = 1.0f - p * t * e;
  return copysignf(r, x);
}

__device__ __forceinline__ float gelu_exact(float f) {
  return 0.5f * f * (1.0f + fast_erf(f * 0.70710678118654752f));
}

__global__ void zero_scalars_kernel(unsigned* p) {
  if (threadIdx.x < 8) p[threadIdx.x] = 0u;
}

// absmax of src[i] * (*smul); block LDS reduce -> ONE atomic per block
__global__ void absmax_kernel(const float* __restrict__ src, int n4,
                              const float* __restrict__ smul,
                              unsigned* __restrict__ dst) {
  __shared__ float red[4];
  const float4* s4 = (const float4*)src;
  const float s = smul ? smul[0] : 1.0f;
  float m = 0.0f;
  const int stride = gridDim.x * blockDim.x;
  for (int i = blockIdx.x * blockDim.x + threadIdx.x; i < n4; i += stride) {
    float4 v = s4[i];
    m = fmaxf(m, fabsf(v.x * s));
    m = fmaxf(m, fabsf(v.y * s));
    m = fmaxf(m, fabsf(v.z * s));
    m = fmaxf(m, fabsf(v.w * s));
  }
  m = wave_max(m);
  if ((threadIdx.x & 63) == 0) red[threadIdx.x >> 6] = m;
  __syncthreads();
  if (threadIdx.x == 0)
    atomicMax(dst, __float_as_uint(fmaxf(fmaxf(red[0], red[1]), fmaxf(red[2], red[3]))));
}

// single-block max over n floats -> dst (float bits)
__global__ void reduce_max_kernel(const float* __restrict__ partial, int n,
                                  unsigned* __restrict__ dst) {
  __shared__ float red[4];
  float m = 0.0f;
  for (int i = threadIdx.x; i < n; i += blockDim.x) m = fmaxf(m, partial[i]);
  m = wave_max(m);
  if ((threadIdx.x & 63) == 0) red[threadIdx.x >> 6] = m;
  __syncthreads();
  if (threadIdx.x == 0)
    dst[0] = __float_as_uint(fmaxf(fmaxf(red[0], red[1]), fmaxf(red[2], red[3])));
}

// q = rint(clip((v*smul)/scale, -128, 127)), scale = maxbits/127 (exact IEEE divide)
__global__ void quantize_kernel(const float* __restrict__ src, int n4,
                                const float* __restrict__ smul,
                                const unsigned* __restrict__ maxbits,
                                int8_t* __restrict__ dst) {
  const float4* s4 = (const float4*)src;
  char4* d4 = (char4*)dst;
  const float s = smul ? smul[0] : 1.0f;
  const float scale = __uint_as_float(maxbits[0]) / 127.0f;
  const int stride = gridDim.x * blockDim.x;
  for (int i = blockIdx.x * blockDim.x + threadIdx.x; i < n4; i += stride) {
    float4 v = s4[i];
    char4 q;
    q.x = (signed char)(int)rintf(fminf(fmaxf((v.x * s) / scale, -128.0f), 127.0f));
    q.y = (signed char)(int)rintf(fminf(fmaxf((v.y * s) / scale, -128.0f), 127.0f));
    q.z = (signed char)(int)rintf(fminf(fmaxf((v.z * s) / scale, -128.0f), 127.0f));
    q.w = (signed char)(int)rintf(fminf(fmaxf((v.w * s) / scale, -128.0f), 127.0f));
    d4[i] = q;
  }
}

// C = A[M,K] @ B[N,K]^T, int8 -> int32 MFMA. BM=BN=128, BK=64, 2x2 waves of 64x64.
// EPI 0: g = gelu((acc+b1)*s1); per-block max(|g|) -> partial[] (plain store)
// EPI 1: store qh = rint(clip(g/s_h)) int8, coalesced via LDS repack
// EPI 2: store out = (acc+b2)*(sw2*sx2) f32
template <int EPI>
__global__ __launch_bounds__(256, 4)
void gemm_i8_kernel(const int8_t* __restrict__ A, const int8_t* __restrict__ B,
                    const float* __restrict__ bias,
                    const unsigned* __restrict__ scal,
                    float* __restrict__ partial,
                    int8_t* __restrict__ out_i8,
                    float* __restrict__ out_f32,
                    int N, int K) {
  __shared__ __align__(16) int8_t lA[2][128 * 64];
  __shared__ __align__(16) int8_t lB[2][128 * 64];
  __shared__ float red[4];

  const int t = threadIdx.x;
  const int lane = t & 63;
  const int wave = t >> 6;
  const int wr = wave >> 1;
  const int wc = wave & 1;
  const size_t m0 = (size_t)blockIdx.x * 128;
  const int n0 = blockIdx.y * 128;

  const int8_t* Ab = A + m0 * (size_t)K;
  const int8_t* Bb = B + (size_t)n0 * (size_t)K;

  v4i acc[4][4] = {};
  const int KT = K >> 6;  // BK = 64

  // Staging: linear LDS fill (base + lane*16), XOR slot-swizzle applied on the
  // GLOBAL source address (rule #21). Rows are 64 B = 4 slots of 16 B.
  const int o0 = t * 16;
  const int row0 = o0 >> 6;                       // rows 0..63 (half tile)
  const int ss = ((o0 >> 4) & 3) ^ (row0 & 3);    // same for row0+64 (row&3 preserved)
  const int ubase = __builtin_amdgcn_readfirstlane((t & 192) * 16);  // wave-uniform
  const size_t srcA0 = (size_t)row0 * K + (size_t)(ss * 16);
  const size_t srcA1 = (size_t)(row0 + 64) * K + (size_t)(ss * 16);

  auto stage = [&](int buf, int kt) {
    const int8_t* ga = Ab + kt * 64;
    const int8_t* gb = Bb + kt * 64;
    __builtin_amdgcn_global_load_lds(GPTR(ga + srcA0), LPTR(&lA[buf][ubase]), 16, 0, 0);
    __builtin_amdgcn_global_load_lds(GPTR(ga + srcA1), LPTR(&lA[buf][4096 + ubase]), 16, 0, 0);
    __builtin_amdgcn_global_load_lds(GPTR(gb + srcA0), LPTR(&lB[buf][ubase]), 16, 0, 0);
    __builtin_amdgcn_global_load_lds(GPTR(gb + srcA1), LPTR(&lB[buf][4096 + ubase]), 16, 0, 0);
  };

  const int r15 = lane & 15;
  const int q4 = lane >> 4;

  auto compute = [&](int buf) {
    v4i af[4], bf[4];
#pragma unroll
    for (int fr = 0; fr < 4; ++fr) {
      const int row = wr * 64 + fr * 16 + r15;
      const int slot = q4 ^ (row & 3);
      af[fr] = *(const v4i*)(&lA[buf][row * 64 + slot * 16]);
    }
#pragma unroll
    for (int fc = 0; fc < 4; ++fc) {
      const int row = wc * 64 + fc * 16 + r15;
      const int slot = q4 ^ (row & 3);
      bf[fc] = *(const v4i*)(&lB[buf][row * 64 + slot * 16]);
    }
#pragma unroll
    for (int fr = 0; fr < 4; ++fr)
#pragma unroll
      for (int fc = 0; fc < 4; ++fc)
        acc[fr][fc] = __builtin_amdgcn_mfma_i32_16x16x64_i8(af[fr], bf[fc], acc[fr][fc], 0, 0, 0);
  };

  stage(0, 0);
  asm volatile("s_waitcnt vmcnt(0)" ::: "memory");
  __syncthreads();
  int cur = 0;
  for (int kt = 1; kt < KT; ++kt) {
    stage(cur ^ 1, kt);   // issue next-tile loads BEFORE compute
    compute(cur);
    __syncthreads();      // drains vmcnt+lgkmcnt: next tile ready
    cur ^= 1;
  }
  compute(cur);

  // Epilogue. C/D mapping (verified r1): col = lane&15, row = (lane>>4)*4 + reg.
  const int rb = q4 * 4;

  if constexpr (EPI == 0) {
    const float sx = __uint_as_float(scal[0]) / 127.0f;
    const float sw = __uint_as_float(scal[1]) / 127.0f;
    const float s1 = sw * sx;
    float lm = 0.0f;
#pragma unroll
    for (int fc = 0; fc < 4; ++fc) {
      const float bv = bias[n0 + wc * 64 + fc * 16 + r15];
#pragma unroll
      for (int fr = 0; fr < 4; ++fr)
#pragma unroll
        for (int r = 0; r < 4; ++r) {
          const float f = ((float)acc[fr][fc][r] + bv) * s1;
          lm = fmaxf(lm, fabsf(gelu_exact(f)));
        }
    }
    lm = wave_max(lm);
    if (lane == 0) red[wave] = lm;
    __syncthreads();
    if (t == 0)
      partial[blockIdx.y * gridDim.x + blockIdx.x] =
          fmaxf(fmaxf(red[0], red[1]), fmaxf(red[2], red[3]));
  } else if constexpr (EPI == 1) {
    const float sx = __uint_as_float(scal[0]) / 127.0f;
    const float sw = __uint_as_float(scal[1]) / 127.0f;
    const float s1 = sw * sx;
    const float sh = __uint_as_float(scal[3]) / 127.0f;
    const float inv_sh = __builtin_amdgcn_rcpf(sh);
    __syncthreads();                 // done reading lA/lB
    int8_t* qt = (int8_t*)lA;        // 16 KiB = 128x128 i8 repack tile
#pragma unroll
    for (int fc = 0; fc < 4; ++fc) {
      const int col = wc * 64 + fc * 16 + r15;
      const float bv = bias[n0 + col];
#pragma unroll
      for (int fr = 0; fr < 4; ++fr)
#pragma unroll
        for (int r = 0; r < 4; ++r) {
          const int row = wr * 64 + fr * 16 + rb + r;
          const float f = ((float)acc[fr][fc][r] + bv) * s1;
          const float g = gelu_exact(f);
          const float qv = rintf(fminf(fmaxf(g * inv_sh, -128.0f), 127.0f));
          qt[row * 128 + col] = (int8_t)(int)qv;
        }
    }
    __syncthreads();
#pragma unroll
    for (int v = 0; v < 4; ++v) {
      const int row = v * 32 + (t >> 3);
      const int colb = (t & 7) * 16;
      *(v4i*)(out_i8 + (m0 + row) * (size_t)N + n0 + colb) =
          *(const v4i*)(qt + row * 128 + colb);
    }
  } else {
    const float sw2 = __uint_as_float(scal[2]) / 127.0f;
    const float sh = __uint_as_float(scal[3]) / 127.0f;
    const float x2max = 127.0f * sh;
    const float sx2 = x2max / 127.0f;
    const float s2 = sw2 * sx2;
#pragma unroll
    for (int fc = 0; fc < 4; ++fc) {
      const int col = n0 + wc * 64 + fc * 16 + r15;
      const float bv = bias[col];
#pragma unroll
      for (int fr = 0; fr < 4; ++fr)
#pragma unroll
        for (int r = 0; r < 4; ++r) {
          const size_t row = m0 + (size_t)(wr * 64 + fr * 16 + rb + r);
          out_f32[row * (size_t)N + col] = ((float)acc[fr][fc][r] + bv) * s2;
        }
    }
  }
}

extern "C" void kernel_launch(void* const* d_in, const int* in_sizes, int n_in,
                              void* d_out, int out_size, void* d_ws, size_t ws_size,
                              hipStream_t stream) {
  const float* x   = (const float*)d_in[0];
  const float* sxp = (const float*)d_in[1];
  const float* w1  = (const float*)d_in[2];
  const float* b1  = (const float*)d_in[3];
  const float* w2  = (const float*)d_in[4];
  const float* b2  = (const float*)d_in[5];

  const int H = in_sizes[3];      // 1536
  const int D = in_sizes[5];      // 384
  const int M = in_sizes[0] / D;  // 25216 = 197*128
  const int GM = M / 128;         // 197

  uint8_t* ws = (uint8_t*)d_ws;
  unsigned* scal = (unsigned*)ws;  // [0]=max|x2| [1]=max|w1| [2]=max|w2| [3]=max|g|
  size_t off = 256;
  float* partial = (float*)(ws + off); off += 16384;  // per-block maxima (<=4096)
  int8_t* qx  = (int8_t*)(ws + off); off += (size_t)M * D;
  int8_t* qw1 = (int8_t*)(ws + off); off += (size_t)H * D;
  int8_t* qw2 = (int8_t*)(ws + off); off += (size_t)D * H;
  int8_t* qh  = (int8_t*)(ws + off); off += (size_t)M * H;
  (void)ws_size; (void)n_in; (void)out_size;

  zero_scalars_kernel<<<1, 64, 0, stream>>>(scal);

  absmax_kernel<<<dim3(512), dim3(256), 0, stream>>>(x, M * D / 4, sxp, scal + 0);
  absmax_kernel<<<dim3(128), dim3(256), 0, stream>>>(w1, H * D / 4, nullptr, scal + 1);
  absmax_kernel<<<dim3(128), dim3(256), 0, stream>>>(w2, D * H / 4, nullptr, scal + 2);

  quantize_kernel<<<dim3(2048), dim3(256), 0, stream>>>(x, M * D / 4, sxp, scal + 0, qx);
  quantize_kernel<<<dim3(256), dim3(256), 0, stream>>>(w1, H * D / 4, nullptr, scal + 1, qw1);
  quantize_kernel<<<dim3(256), dim3(256), 0, stream>>>(w2, D * H / 4, nullptr, scal + 2, qw2);

  dim3 blk(256);
  dim3 g1(GM, H / 128);  // 197 x 12
  gemm_i8_kernel<0><<<g1, blk, 0, stream>>>(qx, qw1, b1, scal, partial, nullptr, nullptr, H, D);
  reduce_max_kernel<<<1, 256, 0, stream>>>(partial, GM * (H / 128), scal + 3);
  gemm_i8_kernel<1><<<g1, blk, 0, stream>>>(qx, qw1, b1, scal, nullptr, qh, nullptr, H, D);

  dim3 g2(GM, D / 128);  // 197 x 3
  gemm_i8_kernel<2><<<g2, blk, 0, stream>>>(qh, qw2, b2, scal, nullptr, nullptr, (float*)d_out, D, H);
}

// Round 3
// 137.168 us; speedup vs baseline: 2.7355x; 1.2112x over previous
//
#include <hip/hip_runtime.h>
#include <hip/hip_bf16.h>
#include <stdint.h>

typedef int v4i __attribute__((ext_vector_type(4)));

#define GPTR(p) ((const __attribute__((address_space(1))) void*)(p))
#define LPTR(p) ((__attribute__((address_space(3))) void*)(p))

__device__ __forceinline__ float wave_max(float m) {
#pragma unroll
  for (int off = 32; off > 0; off >>= 1)
    m = fmaxf(m, __shfl_xor(m, off, 64));
  return m;
}

// branch-free erf (Abramowitz-Stegun 7.1.26), |err| <= 1.5e-7 absolute
__device__ __forceinline__ float fast_erf(float x) {
  const float ax = fabsf(x);
  const float t = __builtin_amdgcn_rcpf(fmaf(0.3275911f, ax, 1.0f));
  float p = fmaf(1.061405429f, t, -1.453152027f);
  p = fmaf(p, t, 1.421413741f);
  p = fmaf(p, t, -0.284496736f);
  p = fmaf(p, t, 0.254829592f);
  const float e = __expf(-ax * ax);
  const float r = 1.0f - p * t * e;
  return copysignf(r, x);
}

__device__ __forceinline__ float gelu_exact(float f) {
  return 0.5f * f * (1.0f + fast_erf(f * 0.70710678118654752f));
}

// fused absmax of {x*smul, w1, w2} -> scal[0..2], one atomic per block
__global__ void absmax3_kernel(const float* __restrict__ x, int nx4,
                               const float* __restrict__ smul,
                               const float* __restrict__ w1, int nw14,
                               const float* __restrict__ w2, int nw24,
                               unsigned* __restrict__ scal) {
  __shared__ float red[4];
  const int bid = blockIdx.x;
  const float4* s4;
  int n4, b0, nb;
  float s = 1.0f;
  unsigned* dst;
  if (bid < 512)      { s4 = (const float4*)x;  n4 = nx4;  s = smul[0]; dst = scal;     b0 = bid;       nb = 512; }
  else if (bid < 640) { s4 = (const float4*)w1; n4 = nw14;              dst = scal + 1; b0 = bid - 512; nb = 128; }
  else                { s4 = (const float4*)w2; n4 = nw24;              dst = scal + 2; b0 = bid - 640; nb = 128; }
  float m = 0.0f;
  const int stride = nb * blockDim.x;
  for (int i = b0 * blockDim.x + threadIdx.x; i < n4; i += stride) {
    float4 v = s4[i];
    m = fmaxf(m, fabsf(v.x * s));
    m = fmaxf(m, fabsf(v.y * s));
    m = fmaxf(m, fabsf(v.z * s));
    m = fmaxf(m, fabsf(v.w * s));
  }
  m = wave_max(m);
  if ((threadIdx.x & 63) == 0) red[threadIdx.x >> 6] = m;
  __syncthreads();
  if (threadIdx.x == 0)
    atomicMax(dst, __float_as_uint(fmaxf(fmaxf(red[0], red[1]), fmaxf(red[2], red[3]))));
}

// fused quantize of {x*smul, w1, w2} -> qx, qw1, qw2
__global__ void quantize3_kernel(const float* __restrict__ x, int nx4,
                                 const float* __restrict__ smul,
                                 const float* __restrict__ w1, int nw14,
                                 const float* __restrict__ w2, int nw24,
                                 const unsigned* __restrict__ scal,
                                 int8_t* __restrict__ qx,
                                 int8_t* __restrict__ qw1,
                                 int8_t* __restrict__ qw2) {
  const int bid = blockIdx.x;
  const float4* s4;
  char4* d4;
  int n4, b0, nb;
  float s = 1.0f, mx;
  if (bid < 2048)      { s4 = (const float4*)x;  d4 = (char4*)qx;  n4 = nx4;  s = smul[0]; mx = __uint_as_float(scal[0]); b0 = bid;        nb = 2048; }
  else if (bid < 2176) { s4 = (const float4*)w1; d4 = (char4*)qw1; n4 = nw14;              mx = __uint_as_float(scal[1]); b0 = bid - 2048; nb = 128; }
  else                 { s4 = (const float4*)w2; d4 = (char4*)qw2; n4 = nw24;              mx = __uint_as_float(scal[2]); b0 = bid - 2176; nb = 128; }
  const float scale = mx / 127.0f;  // exact IEEE divide, matches reference
  const int stride = nb * blockDim.x;
  for (int i = b0 * blockDim.x + threadIdx.x; i < n4; i += stride) {
    float4 v = s4[i];
    char4 q;
    q.x = (signed char)(int)rintf(fminf(fmaxf((v.x * s) / scale, -128.0f), 127.0f));
    q.y = (signed char)(int)rintf(fminf(fmaxf((v.y * s) / scale, -128.0f), 127.0f));
    q.z = (signed char)(int)rintf(fminf(fmaxf((v.z * s) / scale, -128.0f), 127.0f));
    q.w = (signed char)(int)rintf(fminf(fmaxf((v.w * s) / scale, -128.0f), 127.0f));
    d4[i] = q;
  }
}

// reduce partial maxima of raw fc1 output f, then s_h numerator = max|gelu|:
// gelu is increasing for f>0; |gelu| <= max(gelu(max_f), 0.1699702) (global min |gelu|).
__global__ void reduce_scale_kernel(const float* __restrict__ partial, int n,
                                    unsigned* __restrict__ scal) {
  __shared__ float red[4];
  float m = -3.4e38f;
  for (int i = threadIdx.x; i < n; i += blockDim.x) m = fmaxf(m, partial[i]);
  m = wave_max(m);
  if ((threadIdx.x & 63) == 0) red[threadIdx.x >> 6] = m;
  __syncthreads();
  if (threadIdx.x == 0) {
    m = fmaxf(fmaxf(red[0], red[1]), fmaxf(red[2], red[3]));
    const float sx = __uint_as_float(scal[0]) / 127.0f;
    const float sw = __uint_as_float(scal[1]) / 127.0f;
    const float max_f = m * (sw * sx);  // same fp ops as per-element path
    scal[3] = __float_as_uint(fmaxf(gelu_exact(max_f), 0.1699702f));
  }
}

// C = A[M,K] @ B[N,K]^T, int8 -> int32 MFMA. BM=BN=128, BK=64, 2x2 waves of 64x64.
// grid: x = N-tile (fastest, shares A panel), y = M-tile.
// EPI 0: per-block max of f = acc + bias -> partial[] (gelu deferred to reducer)
// EPI 1: store qh = rint(clip(gelu(f*s1)/s_h)) int8, coalesced via LDS repack
// EPI 2: store out = (acc+b2)*(sw2*sx2) f32
template <int EPI>
__global__ __launch_bounds__(256, 4)
void gemm_i8_kernel(const int8_t* __restrict__ A, const int8_t* __restrict__ B,
                    const float* __restrict__ bias,
                    const unsigned* __restrict__ scal,
                    float* __restrict__ partial,
                    int8_t* __restrict__ out_i8,
                    float* __restrict__ out_f32,
                    int N, int K) {
  __shared__ __align__(16) int8_t lA[2][128 * 64];
  __shared__ __align__(16) int8_t lB[2][128 * 64];

  const int t = threadIdx.x;
  const int lane = t & 63;
  const int wave = t >> 6;
  const int wr = wave >> 1;
  const int wc = wave & 1;
  const size_t m0 = (size_t)blockIdx.y * 128;
  const int n0 = blockIdx.x * 128;

  const int8_t* Ab = A + m0 * (size_t)K;
  const int8_t* Bb = B + (size_t)n0 * (size_t)K;

  v4i acc[4][4] = {};
  const int KT = K >> 6;  // BK = 64

  // Staging: linear LDS fill (base + lane*16); XOR slot-swizzle f(row)=(row>>1)&3
  // applied on the GLOBAL source address (both-sides rule). Rows are 64 B = 4
  // slots of 16 B; f must be injective on even rows AND odd rows within each
  // 8-row group so every 8-lane ds_read group covers all 32 banks.
  const int row0 = t >> 2;                       // rows 0..63 (half tile)
  const int ss = (t & 3) ^ ((row0 >> 1) & 3);    // f(row+64)==f(row): preserved
  const int ubase = __builtin_amdgcn_readfirstlane((t & 192) * 16);  // wave-uniform
  const size_t srcA0 = (size_t)row0 * K + (size_t)(ss * 16);
  const size_t srcA1 = (size_t)(row0 + 64) * K + (size_t)(ss * 16);

  auto stage = [&](int buf, int kt) {
    const int8_t* ga = Ab + kt * 64;
    const int8_t* gb = Bb + kt * 64;
    __builtin_amdgcn_global_load_lds(GPTR(ga + srcA0), LPTR(&lA[buf][ubase]), 16, 0, 0);
    __builtin_amdgcn_global_load_lds(GPTR(ga + srcA1), LPTR(&lA[buf][4096 + ubase]), 16, 0, 0);
    __builtin_amdgcn_global_load_lds(GPTR(gb + srcA0), LPTR(&lB[buf][ubase]), 16, 0, 0);
    __builtin_amdgcn_global_load_lds(GPTR(gb + srcA1), LPTR(&lB[buf][4096 + ubase]), 16, 0, 0);
  };

  const int r15 = lane & 15;
  const int q4 = lane >> 4;

  auto compute = [&](int buf) {
    v4i af[4], bf[4];
#pragma unroll
    for (int fr = 0; fr < 4; ++fr) {
      const int row = wr * 64 + fr * 16 + r15;
      const int slot = q4 ^ ((row >> 1) & 3);
      af[fr] = *(const v4i*)(&lA[buf][row * 64 + slot * 16]);
    }
#pragma unroll
    for (int fc = 0; fc < 4; ++fc) {
      const int row = wc * 64 + fc * 16 + r15;
      const int slot = q4 ^ ((row >> 1) & 3);
      bf[fc] = *(const v4i*)(&lB[buf][row * 64 + slot * 16]);
    }
#pragma unroll
    for (int fr = 0; fr < 4; ++fr)
#pragma unroll
      for (int fc = 0; fc < 4; ++fc)
        acc[fr][fc] = __builtin_amdgcn_mfma_i32_16x16x64_i8(af[fr], bf[fc], acc[fr][fc], 0, 0, 0);
  };

  stage(0, 0);
  asm volatile("s_waitcnt vmcnt(0)" ::: "memory");
  __syncthreads();
  int cur = 0;
  for (int kt = 1; kt < KT; ++kt) {
    stage(cur ^ 1, kt);   // issue next-tile loads BEFORE compute
    compute(cur);
    __syncthreads();      // drains vmcnt+lgkmcnt: next tile ready
    cur ^= 1;
  }
  compute(cur);

  // Epilogue. C/D mapping: col = lane&15, row = (lane>>4)*4 + reg.
  const int rb = q4 * 4;

  if constexpr (EPI == 0) {
    float lm = -3.4e38f;
#pragma unroll
    for (int fc = 0; fc < 4; ++fc) {
      const float bv = bias[n0 + wc * 64 + fc * 16 + r15];
#pragma unroll
      for (int fr = 0; fr < 4; ++fr)
#pragma unroll
        for (int r = 0; r < 4; ++r)
          lm = fmaxf(lm, (float)acc[fr][fc][r] + bv);
    }
    lm = wave_max(lm);
    __syncthreads();               // all LDS reads done -> reuse lA
    float* red = (float*)lA;
    if (lane == 0) red[wave] = lm;
    __syncthreads();
    if (t == 0)
      partial[blockIdx.y * gridDim.x + blockIdx.x] =
          fmaxf(fmaxf(red[0], red[1]), fmaxf(red[2], red[3]));
  } else if constexpr (EPI == 1) {
    const float sx = __uint_as_float(scal[0]) / 127.0f;
    const float sw = __uint_as_float(scal[1]) / 127.0f;
    const float s1 = sw * sx;
    const float sh = __uint_as_float(scal[3]) / 127.0f;
    const float inv_sh = __builtin_amdgcn_rcpf(sh);
    __syncthreads();                 // done reading lA/lB
    int8_t* qt = (int8_t*)lA;        // 16 KiB = 128x128 i8 repack tile
#pragma unroll
    for (int fc = 0; fc < 4; ++fc) {
      const int col = wc * 64 + fc * 16 + r15;
      const float bv = bias[n0 + col];
#pragma unroll
      for (int fr = 0; fr < 4; ++fr)
#pragma unroll
        for (int r = 0; r < 4; ++r) {
          const int row = wr * 64 + fr * 16 + rb + r;
          const float f = ((float)acc[fr][fc][r] + bv) * s1;
          const float g = gelu_exact(f);
          const float qv = rintf(fminf(fmaxf(g * inv_sh, -128.0f), 127.0f));
          qt[row * 128 + col] = (int8_t)(int)qv;
        }
    }
    __syncthreads();
#pragma unroll
    for (int v = 0; v < 4; ++v) {
      const int row = v * 32 + (t >> 3);
      const int colb = (t & 7) * 16;
      *(v4i*)(out_i8 + (m0 + row) * (size_t)N + n0 + colb) =
          *(const v4i*)(qt + row * 128 + colb);
    }
  } else {
    const float sw2 = __uint_as_float(scal[2]) / 127.0f;
    const float sh = __uint_as_float(scal[3]) / 127.0f;
    const float x2max = 127.0f * sh;
    const float sx2 = x2max / 127.0f;
    const float s2 = sw2 * sx2;
#pragma unroll
    for (int fc = 0; fc < 4; ++fc) {
      const int col = n0 + wc * 64 + fc * 16 + r15;
      const float bv = bias[col];
#pragma unroll
      for (int fr = 0; fr < 4; ++fr)
#pragma unroll
        for (int r = 0; r < 4; ++r) {
          const size_t row = m0 + (size_t)(wr * 64 + fr * 16 + rb + r);
          out_f32[row * (size_t)N + col] = ((float)acc[fr][fc][r] + bv) * s2;
        }
    }
  }
}

extern "C" void kernel_launch(void* const* d_in, const int* in_sizes, int n_in,
                              void* d_out, int out_size, void* d_ws, size_t ws_size,
                              hipStream_t stream) {
  const float* x   = (const float*)d_in[0];
  const float* sxp = (const float*)d_in[1];
  const float* w1  = (const float*)d_in[2];
  const float* b1  = (const float*)d_in[3];
  const float* w2  = (const float*)d_in[4];
  const float* b2  = (const float*)d_in[5];

  const int H = in_sizes[3];      // 1536
  const int D = in_sizes[5];      // 384
  const int M = in_sizes[0] / D;  // 25216 = 197*128
  const int GM = M / 128;         // 197
  const int GN1 = H / 128;        // 12
  const int GN2 = D / 128;        // 3

  uint8_t* ws = (uint8_t*)d_ws;
  unsigned* scal = (unsigned*)ws;  // [0]=max|x2| [1]=max|w1| [2]=max|w2| [3]=max|g|
  size_t off = 256;
  float* partial = (float*)(ws + off); off += 16384;
  int8_t* qx  = (int8_t*)(ws + off); off += (size_t)M * D;
  int8_t* qw1 = (int8_t*)(ws + off); off += (size_t)H * D;
  int8_t* qw2 = (int8_t*)(ws + off); off += (size_t)D * H;
  int8_t* qh  = (int8_t*)(ws + off); off += (size_t)M * H;
  (void)ws_size; (void)n_in; (void)out_size;

  hipMemsetAsync(scal, 0, 16, stream);

  absmax3_kernel<<<dim3(768), dim3(256), 0, stream>>>(
      x, M * D / 4, sxp, w1, H * D / 4, w2, D * H / 4, scal);

  quantize3_kernel<<<dim3(2304), dim3(256), 0, stream>>>(
      x, M * D / 4, sxp, w1, H * D / 4, w2, D * H / 4, scal, qx, qw1, qw2);

  dim3 blk(256);
  dim3 g1(GN1, GM);  // N-tile fastest: 12 blocks sharing an A panel are adjacent
  gemm_i8_kernel<0><<<g1, blk, 0, stream>>>(qx, qw1, b1, scal, partial, nullptr, nullptr, H, D);
  reduce_scale_kernel<<<1, 256, 0, stream>>>(partial, GM * GN1, scal);
  gemm_i8_kernel<1><<<g1, blk, 0, stream>>>(qx, qw1, b1, scal, nullptr, qh, nullptr, H, D);

  dim3 g2(GN2, GM);  // 3 x 197
  gemm_i8_kernel<2><<<g2, blk, 0, stream>>>(qh, qw2, b2, scal, nullptr, nullptr, (float*)d_out, D, H);
}